// Round 26
// baseline (477.023 us; speedup 1.0000x reference)
//
#include <hip/hip_runtime.h>

#define NN 50000
#define NE 400000
#define DD 128
#define HH 4
#define DHH 32
#define TT 3
#define RR 6
#define LL 2
#define EPSF 1e-5f

typedef unsigned short ushort_t;
typedef unsigned int uint_t;
typedef __attribute__((ext_vector_type(8))) short short8_t;
typedef __attribute__((ext_vector_type(4))) float float4_t;

__device__ inline ushort_t f2bf(float f){
  union { float f; uint_t u; } x; x.f = f;
  uint_t r = x.u + 0x7fffu + ((x.u >> 16) & 1u);
  return (ushort_t)(r >> 16);
}
__device__ inline float bf2f(ushort_t u){
  union { uint_t u; float f; } x; x.u = ((uint_t)u) << 16;
  return x.f;
}
__device__ inline uint_t pack2(float a, float b){
  return (uint_t)f2bf(a) | ((uint_t)f2bf(b) << 16);
}

// ---------------- CSR build ----------------
__global__ void hist_kernel(const int* __restrict__ dst, int* __restrict__ cnt){
  int e = blockIdx.x*256 + threadIdx.x;
  if (e < NE) atomicAdd(&cnt[dst[e]], 1);
}

// chunked 2-pass scan: thread t owns deg[49t .. 49t+48]; 2 barriers total.
__global__ __launch_bounds__(1024) void scan_kernel(const int* __restrict__ deg,
                                                    int* __restrict__ rowptr){
  __shared__ int wsum[16];
  int tid = threadIdx.x, lane = tid & 63, w = tid >> 6;
  const int CH = 49;   // 1024*49 = 50176 >= NN
  int base = tid * CH;
  int tot = 0;
  for (int j=0;j<CH;j++){
    int i = base + j;
    tot += (i < NN) ? deg[i] : 0;
  }
  int s = tot;
  #pragma unroll
  for (int off=1; off<64; off<<=1){ int t = __shfl_up(s, off); if (lane >= off) s += t; }
  if (lane == 63) wsum[w] = s;
  __syncthreads();
  if (w == 0 && lane < 16){
    int t = wsum[lane];
    #pragma unroll
    for (int off=1; off<16; off<<=1){ int u = __shfl_up(t, off); if (lane >= off) t += u; }
    wsum[lane] = t;
  }
  __syncthreads();
  int waveOff = (w == 0) ? 0 : wsum[w-1];
  int run = (s - tot) + waveOff;   // exclusive prefix for this thread's chunk
  if (tid == 0) rowptr[0] = 0;
  for (int j=0;j<CH;j++){
    int i = base + j;
    if (i < NN){ run += deg[i]; rowptr[i+1] = run; }
  }
}

// scatter: packed (src | etype<<27) in CSR order
__global__ void scatter_kernel(const int* __restrict__ dst, const int* __restrict__ src,
                               const int* __restrict__ etype, const int* __restrict__ rowptr,
                               int* __restrict__ cnt, uint_t* __restrict__ sr){
  int e = blockIdx.x*256 + threadIdx.x;
  if (e < NE){
    int d = dst[e];
    int pos = rowptr[d] + atomicAdd(&cnt[d], 1);
    sr[pos] = (uint_t)src[e] | ((uint_t)etype[e] << 27);
  }
}

// ---------------- W prep: FRAGMENT-ORDER bf16 layouts (all weights, one launch) ----------------
__global__ void wprep_kernel(const float* __restrict__ Wk, const float* __restrict__ Wq,
                             const float* __restrict__ Wv, const float* __restrict__ Wa,
                             const float* __restrict__ Watt, const float* __restrict__ Wmsg,
                             ushort_t* __restrict__ Wkf, ushort_t* __restrict__ Wqf,
                             ushort_t* __restrict__ Wvf, ushort_t* __restrict__ Waf,
                             ushort_t* __restrict__ Wattf, ushort_t* __restrict__ Wmsgf){
  int i = blockIdx.x*256 + threadIdx.x;
  if (i < TT*DD*DD){
    int j = i & 7, m = (i>>3)&15, kg = (i>>7)&3, ks = (i>>9)&3, tile = (i>>11)&7, t = i>>14;
    int d = ks*32 + kg*4 + (j&3) + ((j>>2)<<4);
    int o = tile*16 + m;
    size_t srcI = (size_t)t*16384 + (size_t)d*DD + o;
    Wkf[i] = f2bf(Wk[srcI]);
    Wqf[i] = f2bf(Wq[srcI]);
    Wvf[i] = f2bf(Wv[srcI]);
    Waf[i] = f2bf(Wa[srcI]);
  }
  if (i < HH*RR*DHH*DHH){
    int j = i & 7, m = (i>>3)&15, kg = (i>>7)&3;
    int tile = (i>>9) % 12, h = i / 6144;
    int nout = tile*16 + m;
    int r = nout >> 5, dd = nout & 31;
    int k = kg*4 + (j&3) + ((j>>2)<<4);
    Wattf[i] = f2bf(Watt[(((h*RR + r)*DHH + dd)<<5) + k]);
    Wmsgf[i] = f2bf(Wmsg[(((h*RR + r)*DHH + k)<<5) + dd]);
  }
}

// ---------------- fused K/Q/V + qhat + vhat; ping-pong staging (round-24 form) ----------------
__global__ __launch_bounds__(256) void kqv_kernel(
    const float* __restrict__ x, const int* __restrict__ ntype,
    const float* __restrict__ Wk, const float* __restrict__ Wq, const float* __restrict__ Wv,
    const ushort_t* __restrict__ Wkf, const ushort_t* __restrict__ Wqf, const ushort_t* __restrict__ Wvf,
    const ushort_t* __restrict__ Wattf, const ushort_t* __restrict__ Wmsgf,
    const float* __restrict__ pri,
    ushort_t* __restrict__ kout, ushort_t* __restrict__ qh, ushort_t* __restrict__ vhat)
{
  __shared__ int nts[16];
  __shared__ ushort_t smem[24704];      // 49.4 KB
  ushort_t* xs_ = smem;                 // [16][132] phase B (aliased by stg1)
  ushort_t* qs_ = smem + 2112;
  ushort_t* vs_ = smem + 4224;
  ushort_t* ks_ = smem + 6336;          // ends 8448
  ushort_t* stg1 = smem;                // [16][772] staging for qh
  ushort_t* stg2 = smem + 12352;        // [16][772] staging for vhat
  int tid = threadIdx.x;
  int n0 = blockIdx.x * 16;
  if (tid < 16) nts[tid] = ntype[n0 + tid];
  #pragma unroll
  for (int it=0; it<8; it++){
    int i = tid + it*256;
    xs_[(i>>7)*132 + (i&127)] = f2bf(x[(size_t)n0*DD + i]);
  }
  __syncthreads();
  int t0 = nts[0];
  bool uni = true;
  #pragma unroll
  for (int j=1;j<16;j++) uni = uni && (nts[j] == t0);

  int lane = tid & 63;
  union U8 { struct { uint2 lo, hi; } u; short8_t s; uint4 q; };

  if (uni){
    int w = tid >> 6;
    int m = lane & 15, kg = lane >> 4;
    float4_t acck0{0.f,0.f,0.f,0.f}, acck1{0.f,0.f,0.f,0.f};
    float4_t accq0{0.f,0.f,0.f,0.f}, accq1{0.f,0.f,0.f,0.f};
    float4_t accv0{0.f,0.f,0.f,0.f}, accv1{0.f,0.f,0.f,0.f};
    const ushort_t* wkf = Wkf + (size_t)t0*16384;
    const ushort_t* wqf = Wqf + (size_t)t0*16384;
    const ushort_t* wvf = Wvf + (size_t)t0*16384;
    int tA = 2*w, tB = 2*w+1;
    #pragma unroll
    for (int ks=0; ks<4; ks++){
      U8 a_;
      a_.u.lo = *(const uint2*)&xs_[m*132 + ks*32 + kg*4];
      a_.u.hi = *(const uint2*)&xs_[m*132 + ks*32 + kg*4 + 16];
      int offA = (((tA*4 + ks)*4 + kg) << 7) + (m << 3);
      int offB = (((tB*4 + ks)*4 + kg) << 7) + (m << 3);
      U8 bk0, bk1, bq0, bq1, bv0, bv1;
      bk0.q = *(const uint4*)(wkf + offA);
      bk1.q = *(const uint4*)(wkf + offB);
      bq0.q = *(const uint4*)(wqf + offA);
      bq1.q = *(const uint4*)(wqf + offB);
      bv0.q = *(const uint4*)(wvf + offA);
      bv1.q = *(const uint4*)(wvf + offB);
      acck0 = __builtin_amdgcn_mfma_f32_16x16x32_bf16(bk0.s, a_.s, acck0, 0,0,0);
      acck1 = __builtin_amdgcn_mfma_f32_16x16x32_bf16(bk1.s, a_.s, acck1, 0,0,0);
      accq0 = __builtin_amdgcn_mfma_f32_16x16x32_bf16(bq0.s, a_.s, accq0, 0,0,0);
      accq1 = __builtin_amdgcn_mfma_f32_16x16x32_bf16(bq1.s, a_.s, accq1, 0,0,0);
      accv0 = __builtin_amdgcn_mfma_f32_16x16x32_bf16(bv0.s, a_.s, accv0, 0,0,0);
      accv1 = __builtin_amdgcn_mfma_f32_16x16x32_bf16(bv1.s, a_.s, accv1, 0,0,0);
    }
    int cA = tA*16 + (kg<<2), cB = tB*16 + (kg<<2);
    *(uint2*)(&ks_[m*132 + cA]) = make_uint2(pack2(acck0[0],acck0[1]), pack2(acck0[2],acck0[3]));
    *(uint2*)(&ks_[m*132 + cB]) = make_uint2(pack2(acck1[0],acck1[1]), pack2(acck1[2],acck1[3]));
    *(uint2*)(&qs_[m*132 + cA]) = make_uint2(pack2(accq0[0],accq0[1]), pack2(accq0[2],accq0[3]));
    *(uint2*)(&qs_[m*132 + cB]) = make_uint2(pack2(accq1[0],accq1[1]), pack2(accq1[2],accq1[3]));
    *(uint2*)(&vs_[m*132 + cA]) = make_uint2(pack2(accv0[0],accv0[1]), pack2(accv0[2],accv0[3]));
    *(uint2*)(&vs_[m*132 + cB]) = make_uint2(pack2(accv1[0],accv1[1]), pack2(accv1[2],accv1[3]));
  } else {
    int c = tid & 127, nb = (tid >> 7) * 8;
    float ak[8], aq[8], av[8];
    #pragma unroll
    for (int j=0;j<8;j++){ ak[j]=0.f; aq[j]=0.f; av[j]=0.f; }
    #pragma unroll
    for (int j=0;j<8;j++){
      int t = nts[nb+j];
      const float* wk = Wk + (size_t)t*DD*DD + c;
      const float* wq = Wq + (size_t)t*DD*DD + c;
      const float* wv = Wv + (size_t)t*DD*DD + c;
      float sk=0.f, sq=0.f, sv=0.f;
      for (int d=0; d<DD; d++){
        float xv = bf2f(xs_[(nb+j)*132 + d]);
        sk += xv*wk[d*DD];
        sq += xv*wq[d*DD];
        sv += xv*wv[d*DD];
      }
      ak[j]=sk; aq[j]=sq; av[j]=sv;
    }
    #pragma unroll
    for (int j=0;j<8;j++){
      ks_[(nb+j)*132 + c]=f2bf(ak[j]);
      qs_[(nb+j)*132 + c]=f2bf(aq[j]);
      vs_[(nb+j)*132 + c]=f2bf(av[j]);
    }
  }
  __syncthreads();

  // ---- load phase-C A-frags to regs; copy k tile out (coalesced) ----
  int h = tid >> 6;
  int m = lane & 15, kg = lane >> 4;
  U8 aq_, av_;
  aq_.u.lo = *(const uint2*)&qs_[m*132 + (h<<5) + (kg<<2)];
  aq_.u.hi = *(const uint2*)&qs_[m*132 + (h<<5) + (kg<<2) + 16];
  av_.u.lo = *(const uint2*)&vs_[m*132 + (h<<5) + (kg<<2)];
  av_.u.hi = *(const uint2*)&vs_[m*132 + (h<<5) + (kg<<2) + 16];
  {
    int row = tid >> 4, coff = (tid & 15) * 8;
    uint4 kv4;
    kv4.x = *(const uint_t*)&ks_[row*132 + coff];
    kv4.y = *(const uint_t*)&ks_[row*132 + coff + 2];
    kv4.z = *(const uint_t*)&ks_[row*132 + coff + 4];
    kv4.w = *(const uint_t*)&ks_[row*132 + coff + 6];
    *(uint4*)(kout + (size_t)(n0+row)*DD + coff) = kv4;
  }
  __syncthreads();   // phase-B tiles dead; stg1 may overwrite

  const ushort_t* wqb = Wattf + h*(RR*DHH*DHH);
  const ushort_t* wvb = Wmsgf + h*(RR*DHH*DHH);

  // ---- Phase C-q: qhat MFMAs -> stg1 ----
  #pragma unroll
  for (int nt=0; nt<12; nt++){
    int frag = ((nt*4 + kg)<<7) + (m<<3);
    U8 bq_;
    bq_.q = *(const uint4*)(wqb + frag);
    float4_t accq{0.f,0.f,0.f,0.f};
    accq = __builtin_amdgcn_mfma_f32_16x16x32_bf16(bq_.s, aq_.s, accq, 0,0,0);
    int nout0 = nt*16 + (kg<<2);
    int r = nout0 >> 5, dd0 = nout0 & 31;
    float scale = pri[h*RR + r] * 0.17677669529663687f;
    *(uint2*)(&stg1[m*772 + r*DD + (h<<5) + dd0]) =
        make_uint2(pack2(accq[0]*scale, accq[1]*scale), pack2(accq[2]*scale, accq[3]*scale));
  }
  __syncthreads();

  // ---- overlapped: qh copy-out (stg1) + vhat MFMAs (-> stg2) ----
  #pragma unroll
  for (int it=0; it<6; it++){
    int idx = tid + it*256;
    int row = idx / 96;
    int off = (idx - row*96) * 8;
    uint4 q4;
    q4.x = *(const uint_t*)&stg1[row*772 + off];
    q4.y = *(const uint_t*)&stg1[row*772 + off + 2];
    q4.z = *(const uint_t*)&stg1[row*772 + off + 4];
    q4.w = *(const uint_t*)&stg1[row*772 + off + 6];
    *(uint4*)(qh + (size_t)(n0+row)*768 + off) = q4;
  }
  #pragma unroll
  for (int nt=0; nt<12; nt++){
    int frag = ((nt*4 + kg)<<7) + (m<<3);
    U8 bv_;
    bv_.q = *(const uint4*)(wvb + frag);
    float4_t accv{0.f,0.f,0.f,0.f};
    accv = __builtin_amdgcn_mfma_f32_16x16x32_bf16(bv_.s, av_.s, accv, 0,0,0);
    int nout0 = nt*16 + (kg<<2);
    int r = nout0 >> 5, dd0 = nout0 & 31;
    *(uint2*)(&stg2[m*772 + r*DD + (h<<5) + dd0]) =
        make_uint2(pack2(accv[0],accv[1]), pack2(accv[2],accv[3]));
  }
  __syncthreads();

  // ---- vhat copy-out (stg2) ----
  #pragma unroll
  for (int it=0; it<6; it++){
    int idx = tid + it*256;
    int row = idx / 96;
    int off = (idx - row*96) * 8;
    uint4 v4;
    v4.x = *(const uint_t*)&stg2[row*772 + off];
    v4.y = *(const uint_t*)&stg2[row*772 + off + 2];
    v4.z = *(const uint_t*)&stg2[row*772 + off + 4];
    v4.w = *(const uint_t*)&stg2[row*772 + off + 6];
    *(uint4*)(vhat + (size_t)(n0+row)*768 + off) = v4;
  }
}

// ---------------- fused logits + online-softmax + vhat-reduce (wave/node, 8-wide) ----------------
__global__ __launch_bounds__(256) void reduce_kernel(
    const ushort_t* __restrict__ kb, const ushort_t* __restrict__ qh,
    const ushort_t* __restrict__ vhat,
    const int* __restrict__ rowptr, const uint_t* __restrict__ src_r,
    ushort_t* __restrict__ agg16)
{
  int n = blockIdx.x*4 + (threadIdx.x >> 6);
  if (n >= NN) return;
  int lane = threadIdx.x & 63;
  int b = rowptr[n], e1 = rowptr[n+1];
  const uint_t* qbase = (const uint_t*)(qh + (size_t)n*RR*DD) + lane;
  uint_t qn0 = qbase[0*64], qn1 = qbase[1*64], qn2 = qbase[2*64];
  uint_t qn3 = qbase[3*64], qn4 = qbase[4*64], qn5 = qbase[5*64];
  float m = -1e30f, den = 0.f, ac0 = 0.f, ac1 = 0.f;
  for (int i=b; i<e1; i+=8){
    int m8 = e1 - i; if (m8 > 8) m8 = 8;
    uint_t sr8[8];
    #pragma unroll
    for (int jj=0;jj<8;jj++) sr8[jj] = src_r[i + ((jj < m8) ? jj : (m8-1))];
    uint_t kk8[8], vv8[8];
    #pragma unroll
    for (int jj=0;jj<8;jj++){
      uint_t sr_ = sr8[jj];
      size_t s = (size_t)(sr_ & 0x07FFFFFFu);
      kk8[jj] = *(const uint_t*)(kb + s*DD + (lane<<1));
      vv8[jj] = *(const uint_t*)(vhat + (s*RR + (sr_>>27))*DD + (lane<<1));
    }
    float p8[8];
    #pragma unroll
    for (int jj=0;jj<8;jj++){
      int r = (int)(sr8[jj] >> 27);
      uint_t qw = qn0;
      qw = (r==1) ? qn1 : qw;
      qw = (r==2) ? qn2 : qw;
      qw = (r==3) ? qn3 : qw;
      qw = (r==4) ? qn4 : qw;
      qw = (r==5) ? qn5 : qw;
      uint_t kw = kk8[jj];
      float pp = bf2f((ushort_t)(kw & 0xffffu))*bf2f((ushort_t)(qw & 0xffffu))
               + bf2f((ushort_t)(kw >> 16))   *bf2f((ushort_t)(qw >> 16));
      #pragma unroll
      for (int off=1; off<16; off<<=1) pp += __shfl_xor(pp, off);
      p8[jj] = (jj < m8) ? pp : -1e30f;
    }
    float mb = p8[0];
    #pragma unroll
    for (int jj=1;jj<8;jj++) mb = fmaxf(mb, p8[jj]);
    float mnew = fmaxf(m, mb);
    float corr = __expf(m - mnew);
    den *= corr; ac0 *= corr; ac1 *= corr;
    m = mnew;
    #pragma unroll
    for (int jj=0;jj<8;jj++){
      float ex = __expf(p8[jj] - m);
      den += ex;
      ac0 += ex * bf2f((ushort_t)(vv8[jj] & 0xffffu));
      ac1 += ex * bf2f((ushort_t)(vv8[jj] >> 16));
    }
  }
  float inv = (den > 0.f) ? 1.f/den : 0.f;
  uint_t packed = (uint_t)f2bf(ac0*inv) | ((uint_t)f2bf(ac1*inv) << 16);
  *(uint_t*)(agg16 + (size_t)n*DD + (lane<<1)) = packed;
}

// ---------------- Wa GEMM via MFMA + skip gate + LayerNorm (+ optional final mix+LN) ----------------
__global__ __launch_bounds__(256) void ha_kernel(
    const ushort_t* __restrict__ agg16, const float* __restrict__ x, const int* __restrict__ ntype,
    const float* __restrict__ Wa, const ushort_t* __restrict__ Waf, const float* __restrict__ skipl,
    const float* __restrict__ lng, const float* __restrict__ lnb,
    const float* __restrict__ out0p, const float* __restrict__ aggw,
    const float* __restrict__ fg, const float* __restrict__ fb, int isFinal,
    float* __restrict__ xout)
{
  __shared__ ushort_t as[16][132];
  __shared__ float xs[16][132];
  __shared__ int nts[16];
  int tid = threadIdx.x;
  int n0 = blockIdx.x * 16;
  {
    int row = tid >> 4, col = (tid & 15) * 8;
    uint4 t4 = *(const uint4*)(agg16 + (size_t)(n0+row)*DD + col);
    *(uint2*)&as[row][col]   = make_uint2(t4.x, t4.y);
    *(uint2*)&as[row][col+4] = make_uint2(t4.z, t4.w);
  }
  if (tid < 16) nts[tid] = ntype[n0 + tid];
  __syncthreads();
  int t0 = nts[0];
  bool uni = true;
  #pragma unroll
  for (int j=1;j<16;j++) uni = uni && (nts[j] == t0);

  if (uni){
    int lane = tid & 63, w = tid >> 6;
    int m = lane & 15, kg = lane >> 4;
    float4_t acc0{0.f,0.f,0.f,0.f}, acc1{0.f,0.f,0.f,0.f};
    const ushort_t* waf = Waf + (size_t)t0*16384;
    int tA = 2*w, tB = 2*w+1;
    union U8 { struct { uint2 lo, hi; } u; short8_t s; uint4 q; };
    #pragma unroll
    for (int ks=0; ks<4; ks++){
      U8 a_;
      a_.u.lo = *(const uint2*)&as[m][ks*32 + kg*4];
      a_.u.hi = *(const uint2*)&as[m][ks*32 + kg*4 + 16];
      U8 b0, b1;
      b0.q = *(const uint4*)(waf + ((((tA*4 + ks)*4 + kg) << 7) + (m << 3)));
      b1.q = *(const uint4*)(waf + ((((tB*4 + ks)*4 + kg) << 7) + (m << 3)));
      acc0 = __builtin_amdgcn_mfma_f32_16x16x32_bf16(b0.s, a_.s, acc0, 0,0,0);
      acc1 = __builtin_amdgcn_mfma_f32_16x16x32_bf16(b1.s, a_.s, acc1, 0,0,0);
    }
    float sk = 1.f/(1.f + __expf(-skipl[t0]));
    int cA = tA*16 + (kg<<2), cB = tB*16 + (kg<<2);
    #pragma unroll
    for (int i=0;i<4;i++){
      float xva = x[(size_t)(n0+m)*DD + cA + i];
      float xvb = x[(size_t)(n0+m)*DD + cB + i];
      xs[m][cA+i] = acc0[i]*sk + xva*(2.f - sk);
      xs[m][cB+i] = acc1[i]*sk + xvb*(2.f - sk);
    }
  } else {
    int c = tid & 127, nb = (tid >> 7) * 8;
    float acc[8];
    #pragma unroll
    for (int j=0;j<8;j++) acc[j]=0.f;
    #pragma unroll
    for (int j=0;j<8;j++){
      int t = nts[nb+j];
      const float* wa = Wa + (size_t)t*DD*DD + c;
      float sacc2 = 0.f;
      for (int d=0; d<DD; d++)
        sacc2 += bf2f(as[nb+j][d]) * wa[d*DD];
      acc[j] = sacc2;
    }
    #pragma unroll
    for (int j=0;j<8;j++){
      int n = n0 + nb + j;
      float sk2 = 1.f/(1.f + __expf(-skipl[nts[nb+j]]));
      float xv = x[(size_t)n*DD + c];
      xs[nb+j][c] = acc[j]*sk2 + xv*(2.f - sk2);
    }
  }
  __syncthreads();
  int lane = tid & 63;
  int r0 = tid >> 6;
  #pragma unroll
  for (int rr = r0; rr < 16; rr += 4){
    float t0v = xs[rr][lane], t1v = xs[rr][lane+64];
    float s = t0v + t1v;
    #pragma unroll
    for (int off=32; off>0; off>>=1) s += __shfl_xor(s, off);
    float mu = s * (1.f/DD);
    float d0 = t0v-mu, d1 = t1v-mu;
    float vs = d0*d0 + d1*d1;
    #pragma unroll
    for (int off=32; off>0; off>>=1) vs += __shfl_xor(vs, off);
    float inv = rsqrtf(vs*(1.f/DD) + EPSF);
    size_t base = (size_t)(n0+rr)*DD;
    float z0 = d0*inv*lng[lane]    + lnb[lane];
    float z1 = d1*inv*lng[lane+64] + lnb[lane+64];
    if (!isFinal){
      xout[base+lane]    = z0;
      xout[base+lane+64] = z1;
    } else {
      float a0 = aggw[0], a1 = aggw[1];
      float mm = fmaxf(a0, a1);
      float e0 = __expf(a0-mm), e1 = __expf(a1-mm);
      float i01 = 1.f/(e0+e1);
      float w0 = e0*i01, w1 = e1*i01;
      float u0 = w0*out0p[base+lane]    + w1*z0;
      float u1 = w0*out0p[base+lane+64] + w1*z1;
      float ss = u0 + u1;
      #pragma unroll
      for (int off=32; off>0; off>>=1) ss += __shfl_xor(ss, off);
      float mu2 = ss * (1.f/DD);
      float f0 = u0-mu2, f1 = u1-mu2;
      float vs2 = f0*f0 + f1*f1;
      #pragma unroll
      for (int off=32; off>0; off>>=1) vs2 += __shfl_xor(vs2, off);
      float inv2 = rsqrtf(vs2*(1.f/DD) + EPSF);
      xout[base+lane]    = f0*inv2*fg[lane]    + fb[lane];
      xout[base+lane+64] = f1*inv2*fg[lane+64] + fb[lane+64];
    }
  }
}

extern "C" void kernel_launch(void* const* d_in, const int* in_sizes, int n_in,
                              void* d_out, int out_size, void* d_ws, size_t ws_size,
                              hipStream_t stream)
{
  (void)in_sizes; (void)n_in; (void)out_size; (void)ws_size;
  const float* h_in  = (const float*)d_in[0];
  const int*   src   = (const int*)d_in[1];
  const int*   dst   = (const int*)d_in[2];
  const int*   ntype = (const int*)d_in[3];
  const int*   etype = (const int*)d_in[4];
  const float* Wk    = (const float*)d_in[5];
  const float* Wq    = (const float*)d_in[6];
  const float* Wv    = (const float*)d_in[7];
  const float* Wa    = (const float*)d_in[8];
  const float* Watt  = (const float*)d_in[9];
  const float* Wmsg  = (const float*)d_in[10];
  const float* pri   = (const float*)d_in[11];
  const float* skp   = (const float*)d_in[12];
  const float* lng   = (const float*)d_in[13];
  const float* lnb   = (const float*)d_in[14];
  const float* aggw  = (const float*)d_in[15];
  const float* aggg  = (const float*)d_in[16];
  const float* aggb_ = (const float*)d_in[17];

  size_t P = (size_t)NN*DD;
  ushort_t* kb16 = (ushort_t*)d_ws;                 // P bf16
  ushort_t* qh   = kb16 + P;                        // N*R*D bf16
  ushort_t* vhat = qh + (size_t)NN*RR*DD;           // N*R*D bf16
  ushort_t* agg16 = vhat + (size_t)NN*RR*DD;        // P bf16
  float* out0  = (float*)(agg16 + P);               // P f32
  int* rowptr = (int*)(out0 + P);
  int* cnt    = rowptr + NN + 1;
  uint_t* srcr = (uint_t*)(cnt + NN);               // NE packed
  ushort_t* wkF = (ushort_t*)(srcr + NE);           // T*D*D bf16 each (fragment order)
  ushort_t* wqF = wkF + (size_t)TT*DD*DD;
  ushort_t* wvF = wqF + (size_t)TT*DD*DD;
  ushort_t* waF = wvF + (size_t)TT*DD*DD;
  ushort_t* wattF = waF + (size_t)TT*DD*DD;         // H*R*32*32 bf16 (fragment order)
  ushort_t* wmsgF = wattF + (size_t)HH*RR*DHH*DHH;  // H*R*32*32 bf16 (fragment order)
  float* xout = (float*)d_out;

  // CSR by dst
  hipMemsetAsync(cnt, 0, NN*sizeof(int), stream);
  hist_kernel<<<(NE+255)/256, 256, 0, stream>>>(dst, cnt);
  scan_kernel<<<1, 1024, 0, stream>>>(cnt, rowptr);
  hipMemsetAsync(cnt, 0, NN*sizeof(int), stream);
  scatter_kernel<<<(NE+255)/256, 256, 0, stream>>>(dst, src, etype, rowptr, cnt, srcr);

  const float* x = h_in;
  for (int l=0; l<LL; l++){
    const float* Wk_l  = Wk  + (size_t)l*TT*DD*DD;
    const float* Wq_l  = Wq  + (size_t)l*TT*DD*DD;
    const float* Wv_l  = Wv  + (size_t)l*TT*DD*DD;
    const float* Wa_l  = Wa  + (size_t)l*TT*DD*DD;
    const float* Wat_l = Watt + (size_t)l*HH*RR*DHH*DHH;
    const float* Wms_l = Wmsg + (size_t)l*HH*RR*DHH*DHH;
    const float* pri_l = pri + (size_t)l*HH*RR;
    const float* skp_l = skp + (size_t)l*TT;

    wprep_kernel<<<(TT*DD*DD+255)/256, 256, 0, stream>>>(Wk_l, Wq_l, Wv_l, Wa_l, Wat_l, Wms_l,
                                                         wkF, wqF, wvF, waF, wattF, wmsgF);
    kqv_kernel<<<NN/16, 256, 0, stream>>>(x, ntype, Wk_l, Wq_l, Wv_l, wkF, wqF, wvF,
                                          wattF, wmsgF, pri_l, kb16, qh, vhat);
    reduce_kernel<<<(NN+3)/4, 256, 0, stream>>>(kb16, qh, vhat, rowptr, srcr, agg16);
    float* xo = (l == 0) ? out0 : xout;
    ha_kernel<<<NN/16, 256, 0, stream>>>(agg16, x, ntype, Wa_l, waF, skp_l,
                                         lng + (size_t)l*DD, lnb + (size_t)l*DD,
                                         out0, aggw, aggg, aggb_, (l == LL-1) ? 1 : 0, xo);
    x = xo;
  }
}

// Round 27
// 476.174 us; speedup vs baseline: 1.0018x; 1.0018x over previous
//
#include <hip/hip_runtime.h>

#define NN 50000
#define NE 400000
#define DD 128
#define HH 4
#define DHH 32
#define TT 3
#define RR 6
#define LL 2
#define EPSF 1e-5f

typedef unsigned short ushort_t;
typedef unsigned int uint_t;
typedef __attribute__((ext_vector_type(8))) short short8_t;
typedef __attribute__((ext_vector_type(4))) float float4_t;

__device__ inline ushort_t f2bf(float f){
  union { float f; uint_t u; } x; x.f = f;
  uint_t r = x.u + 0x7fffu + ((x.u >> 16) & 1u);
  return (ushort_t)(r >> 16);
}
__device__ inline float bf2f(ushort_t u){
  union { uint_t u; float f; } x; x.u = ((uint_t)u) << 16;
  return x.f;
}
__device__ inline uint_t pack2(float a, float b){
  return (uint_t)f2bf(a) | ((uint_t)f2bf(b) << 16);
}

// ---------------- CSR build ----------------
__global__ void hist_kernel(const int* __restrict__ dst, int* __restrict__ cnt){
  int e = blockIdx.x*256 + threadIdx.x;
  if (e < NE) atomicAdd(&cnt[dst[e]], 1);
}

// chunked 2-pass scan: thread t owns deg[49t .. 49t+48]; 2 barriers total.
__global__ __launch_bounds__(1024) void scan_kernel(const int* __restrict__ deg,
                                                    int* __restrict__ rowptr){
  __shared__ int wsum[16];
  int tid = threadIdx.x, lane = tid & 63, w = tid >> 6;
  const int CH = 49;   // 1024*49 = 50176 >= NN
  int base = tid * CH;
  int tot = 0;
  for (int j=0;j<CH;j++){
    int i = base + j;
    tot += (i < NN) ? deg[i] : 0;
  }
  int s = tot;
  #pragma unroll
  for (int off=1; off<64; off<<=1){ int t = __shfl_up(s, off); if (lane >= off) s += t; }
  if (lane == 63) wsum[w] = s;
  __syncthreads();
  if (w == 0 && lane < 16){
    int t = wsum[lane];
    #pragma unroll
    for (int off=1; off<16; off<<=1){ int u = __shfl_up(t, off); if (lane >= off) t += u; }
    wsum[lane] = t;
  }
  __syncthreads();
  int waveOff = (w == 0) ? 0 : wsum[w-1];
  int run = (s - tot) + waveOff;   // exclusive prefix for this thread's chunk
  if (tid == 0) rowptr[0] = 0;
  for (int j=0;j<CH;j++){
    int i = base + j;
    if (i < NN){ run += deg[i]; rowptr[i+1] = run; }
  }
}

// scatter: packed (src | etype<<27) in CSR order
__global__ void scatter_kernel(const int* __restrict__ dst, const int* __restrict__ src,
                               const int* __restrict__ etype, const int* __restrict__ rowptr,
                               int* __restrict__ cnt, uint_t* __restrict__ sr){
  int e = blockIdx.x*256 + threadIdx.x;
  if (e < NE){
    int d = dst[e];
    int pos = rowptr[d] + atomicAdd(&cnt[d], 1);
    sr[pos] = (uint_t)src[e] | ((uint_t)etype[e] << 27);
  }
}

// ---------------- W prep: FRAGMENT-ORDER bf16 layouts (Wk,Wq,Wv,Wa) ----------------
__global__ void wprep_kernel(const float* __restrict__ Wk, const float* __restrict__ Wq,
                             const float* __restrict__ Wv, const float* __restrict__ Wa,
                             ushort_t* __restrict__ Wkf, ushort_t* __restrict__ Wqf,
                             ushort_t* __restrict__ Wvf, ushort_t* __restrict__ Waf){
  int i = blockIdx.x*256 + threadIdx.x;
  if (i < TT*DD*DD){
    int j = i & 7, m = (i>>3)&15, kg = (i>>7)&3, ks = (i>>9)&3, tile = (i>>11)&7, t = i>>14;
    int d = ks*32 + kg*4 + (j&3) + ((j>>2)<<4);
    int o = tile*16 + m;
    size_t srcI = (size_t)t*16384 + (size_t)d*DD + o;
    Wkf[i] = f2bf(Wk[srcI]);
    Wqf[i] = f2bf(Wq[srcI]);
    Wvf[i] = f2bf(Wv[srcI]);
    Waf[i] = f2bf(Wa[srcI]);
  }
}

__global__ void wprep2_kernel(const float* __restrict__ Watt, const float* __restrict__ Wmsg,
                              ushort_t* __restrict__ Wattf, ushort_t* __restrict__ Wmsgf){
  int i = blockIdx.x*256 + threadIdx.x;
  if (i < HH*RR*DHH*DHH){
    int j = i & 7, m = (i>>3)&15, kg = (i>>7)&3;
    int tile = (i>>9) % 12, h = i / 6144;
    int nout = tile*16 + m;
    int r = nout >> 5, dd = nout & 31;
    int k = kg*4 + (j&3) + ((j>>2)<<4);
    Wattf[i] = f2bf(Watt[(((h*RR + r)*DHH + dd)<<5) + k]);
    Wmsgf[i] = f2bf(Wmsg[(((h*RR + r)*DHH + k)<<5) + dd]);
  }
}

// ---------------- fused K/Q/V + qhat + vhat; ping-pong staging, L2-resident stores ----------------
__global__ __launch_bounds__(256) void kqv_kernel(
    const float* __restrict__ x, const int* __restrict__ ntype,
    const float* __restrict__ Wk, const float* __restrict__ Wq, const float* __restrict__ Wv,
    const ushort_t* __restrict__ Wkf, const ushort_t* __restrict__ Wqf, const ushort_t* __restrict__ Wvf,
    const ushort_t* __restrict__ Wattf, const ushort_t* __restrict__ Wmsgf,
    const float* __restrict__ pri,
    ushort_t* __restrict__ kout, ushort_t* __restrict__ qh, ushort_t* __restrict__ vhat)
{
  __shared__ int nts[16];
  __shared__ ushort_t smem[24704];      // 49.4 KB
  ushort_t* xs_ = smem;                 // [16][132] phase B (aliased by stg1)
  ushort_t* qs_ = smem + 2112;
  ushort_t* vs_ = smem + 4224;
  ushort_t* ks_ = smem + 6336;          // ends 8448
  ushort_t* stg1 = smem;                // [16][772] staging for qh
  ushort_t* stg2 = smem + 12352;        // [16][772] staging for vhat
  int tid = threadIdx.x;
  int n0 = blockIdx.x * 16;
  if (tid < 16) nts[tid] = ntype[n0 + tid];
  #pragma unroll
  for (int it=0; it<8; it++){
    int i = tid + it*256;
    xs_[(i>>7)*132 + (i&127)] = f2bf(x[(size_t)n0*DD + i]);
  }
  __syncthreads();
  int t0 = nts[0];
  bool uni = true;
  #pragma unroll
  for (int j=1;j<16;j++) uni = uni && (nts[j] == t0);

  int lane = tid & 63;
  union U8 { struct { uint2 lo, hi; } u; short8_t s; uint4 q; };

  if (uni){
    int w = tid >> 6;
    int m = lane & 15, kg = lane >> 4;
    float4_t acck0{0.f,0.f,0.f,0.f}, acck1{0.f,0.f,0.f,0.f};
    float4_t accq0{0.f,0.f,0.f,0.f}, accq1{0.f,0.f,0.f,0.f};
    float4_t accv0{0.f,0.f,0.f,0.f}, accv1{0.f,0.f,0.f,0.f};
    const ushort_t* wkf = Wkf + (size_t)t0*16384;
    const ushort_t* wqf = Wqf + (size_t)t0*16384;
    const ushort_t* wvf = Wvf + (size_t)t0*16384;
    int tA = 2*w, tB = 2*w+1;
    #pragma unroll
    for (int ks=0; ks<4; ks++){
      U8 a_;
      a_.u.lo = *(const uint2*)&xs_[m*132 + ks*32 + kg*4];
      a_.u.hi = *(const uint2*)&xs_[m*132 + ks*32 + kg*4 + 16];
      int offA = (((tA*4 + ks)*4 + kg) << 7) + (m << 3);
      int offB = (((tB*4 + ks)*4 + kg) << 7) + (m << 3);
      U8 bk0, bk1, bq0, bq1, bv0, bv1;
      bk0.q = *(const uint4*)(wkf + offA);
      bk1.q = *(const uint4*)(wkf + offB);
      bq0.q = *(const uint4*)(wqf + offA);
      bq1.q = *(const uint4*)(wqf + offB);
      bv0.q = *(const uint4*)(wvf + offA);
      bv1.q = *(const uint4*)(wvf + offB);
      acck0 = __builtin_amdgcn_mfma_f32_16x16x32_bf16(bk0.s, a_.s, acck0, 0,0,0);
      acck1 = __builtin_amdgcn_mfma_f32_16x16x32_bf16(bk1.s, a_.s, acck1, 0,0,0);
      accq0 = __builtin_amdgcn_mfma_f32_16x16x32_bf16(bq0.s, a_.s, accq0, 0,0,0);
      accq1 = __builtin_amdgcn_mfma_f32_16x16x32_bf16(bq1.s, a_.s, accq1, 0,0,0);
      accv0 = __builtin_amdgcn_mfma_f32_16x16x32_bf16(bv0.s, a_.s, accv0, 0,0,0);
      accv1 = __builtin_amdgcn_mfma_f32_16x16x32_bf16(bv1.s, a_.s, accv1, 0,0,0);
    }
    int cA = tA*16 + (kg<<2), cB = tB*16 + (kg<<2);
    *(uint2*)(&ks_[m*132 + cA]) = make_uint2(pack2(acck0[0],acck0[1]), pack2(acck0[2],acck0[3]));
    *(uint2*)(&ks_[m*132 + cB]) = make_uint2(pack2(acck1[0],acck1[1]), pack2(acck1[2],acck1[3]));
    *(uint2*)(&qs_[m*132 + cA]) = make_uint2(pack2(accq0[0],accq0[1]), pack2(accq0[2],accq0[3]));
    *(uint2*)(&qs_[m*132 + cB]) = make_uint2(pack2(accq1[0],accq1[1]), pack2(accq1[2],accq1[3]));
    *(uint2*)(&vs_[m*132 + cA]) = make_uint2(pack2(accv0[0],accv0[1]), pack2(accv0[2],accv0[3]));
    *(uint2*)(&vs_[m*132 + cB]) = make_uint2(pack2(accv1[0],accv1[1]), pack2(accv1[2],accv1[3]));
  } else {
    int c = tid & 127, nb = (tid >> 7) * 8;
    float ak[8], aq[8], av[8];
    #pragma unroll
    for (int j=0;j<8;j++){ ak[j]=0.f; aq[j]=0.f; av[j]=0.f; }
    #pragma unroll
    for (int j=0;j<8;j++){
      int t = nts[nb+j];
      const float* wk = Wk + (size_t)t*DD*DD + c;
      const float* wq = Wq + (size_t)t*DD*DD + c;
      const float* wv = Wv + (size_t)t*DD*DD + c;
      float sk=0.f, sq=0.f, sv=0.f;
      for (int d=0; d<DD; d++){
        float xv = bf2f(xs_[(nb+j)*132 + d]);
        sk += xv*wk[d*DD];
        sq += xv*wq[d*DD];
        sv += xv*wv[d*DD];
      }
      ak[j]=sk; aq[j]=sq; av[j]=sv;
    }
    #pragma unroll
    for (int j=0;j<8;j++){
      ks_[(nb+j)*132 + c]=f2bf(ak[j]);
      qs_[(nb+j)*132 + c]=f2bf(aq[j]);
      vs_[(nb+j)*132 + c]=f2bf(av[j]);
    }
  }
  __syncthreads();

  // ---- load phase-C A-frags to regs; copy k tile out (coalesced) ----
  int h = tid >> 6;
  int m = lane & 15, kg = lane >> 4;
  U8 aq_, av_;
  aq_.u.lo = *(const uint2*)&qs_[m*132 + (h<<5) + (kg<<2)];
  aq_.u.hi = *(const uint2*)&qs_[m*132 + (h<<5) + (kg<<2) + 16];
  av_.u.lo = *(const uint2*)&vs_[m*132 + (h<<5) + (kg<<2)];
  av_.u.hi = *(const uint2*)&vs_[m*132 + (h<<5) + (kg<<2) + 16];
  {
    int row = tid >> 4, coff = (tid & 15) * 8;
    uint4 kv4;
    kv4.x = *(const uint_t*)&ks_[row*132 + coff];
    kv4.y = *(const uint_t*)&ks_[row*132 + coff + 2];
    kv4.z = *(const uint_t*)&ks_[row*132 + coff + 4];
    kv4.w = *(const uint_t*)&ks_[row*132 + coff + 6];
    *(uint4*)(kout + (size_t)(n0+row)*DD + coff) = kv4;
  }
  __syncthreads();   // phase-B tiles dead; stg1 may overwrite

  const ushort_t* wqb = Wattf + h*(RR*DHH*DHH);
  const ushort_t* wvb = Wmsgf + h*(RR*DHH*DHH);

  // ---- Phase C-q: qhat MFMAs -> stg1 ----
  #pragma unroll
  for (int nt=0; nt<12; nt++){
    int frag = ((nt*4 + kg)<<7) + (m<<3);
    U8 bq_;
    bq_.q = *(const uint4*)(wqb + frag);
    float4_t accq{0.f,0.f,0.f,0.f};
    accq = __builtin_amdgcn_mfma_f32_16x16x32_bf16(bq_.s, aq_.s, accq, 0,0,0);
    int nout0 = nt*16 + (kg<<2);
    int r = nout0 >> 5, dd0 = nout0 & 31;
    float scale = pri[h*RR + r] * 0.17677669529663687f;
    *(uint2*)(&stg1[m*772 + r*DD + (h<<5) + dd0]) =
        make_uint2(pack2(accq[0]*scale, accq[1]*scale), pack2(accq[2]*scale, accq[3]*scale));
  }
  __syncthreads();

  // ---- overlapped: qh copy-out (stg1) + vhat MFMAs (-> stg2) ----
  #pragma unroll
  for (int it=0; it<6; it++){
    int idx = tid + it*256;
    int row = idx / 96;
    int off = (idx - row*96) * 8;
    uint4 q4;
    q4.x = *(const uint_t*)&stg1[row*772 + off];
    q4.y = *(const uint_t*)&stg1[row*772 + off + 2];
    q4.z = *(const uint_t*)&stg1[row*772 + off + 4];
    q4.w = *(const uint_t*)&stg1[row*772 + off + 6];
    *(uint4*)(qh + (size_t)(n0+row)*768 + off) = q4;
  }
  #pragma unroll
  for (int nt=0; nt<12; nt++){
    int frag = ((nt*4 + kg)<<7) + (m<<3);
    U8 bv_;
    bv_.q = *(const uint4*)(wvb + frag);
    float4_t accv{0.f,0.f,0.f,0.f};
    accv = __builtin_amdgcn_mfma_f32_16x16x32_bf16(bv_.s, av_.s, accv, 0,0,0);
    int nout0 = nt*16 + (kg<<2);
    int r = nout0 >> 5, dd0 = nout0 & 31;
    *(uint2*)(&stg2[m*772 + r*DD + (h<<5) + dd0]) =
        make_uint2(pack2(accv[0],accv[1]), pack2(accv[2],accv[3]));
  }
  __syncthreads();

  // ---- vhat copy-out (stg2) ----
  #pragma unroll
  for (int it=0; it<6; it++){
    int idx = tid + it*256;
    int row = idx / 96;
    int off = (idx - row*96) * 8;
    uint4 v4;
    v4.x = *(const uint_t*)&stg2[row*772 + off];
    v4.y = *(const uint_t*)&stg2[row*772 + off + 2];
    v4.z = *(const uint_t*)&stg2[row*772 + off + 4];
    v4.w = *(const uint_t*)&stg2[row*772 + off + 6];
    *(uint4*)(vhat + (size_t)(n0+row)*768 + off) = v4;
  }
}

// ---------------- fused logits + online-softmax + vhat-reduce (wave/node, 8-wide) ----------------
__global__ __launch_bounds__(256) void reduce_kernel(
    const ushort_t* __restrict__ kb, const ushort_t* __restrict__ qh,
    const ushort_t* __restrict__ vhat,
    const int* __restrict__ rowptr, const uint_t* __restrict__ src_r,
    ushort_t* __restrict__ agg16)
{
  int n = blockIdx.x*4 + (threadIdx.x >> 6);
  if (n >= NN) return;
  int lane = threadIdx.x & 63;
  int b = rowptr[n], e1 = rowptr[n+1];
  const uint_t* qbase = (const uint_t*)(qh + (size_t)n*RR*DD) + lane;
  uint_t qn0 = qbase[0*64], qn1 = qbase[1*64], qn2 = qbase[2*64];
  uint_t qn3 = qbase[3*64], qn4 = qbase[4*64], qn5 = qbase[5*64];
  float m = -1e30f, den = 0.f, ac0 = 0.f, ac1 = 0.f;
  for (int i=b; i<e1; i+=8){
    int m8 = e1 - i; if (m8 > 8) m8 = 8;
    uint_t sr8[8];
    #pragma unroll
    for (int jj=0;jj<8;jj++) sr8[jj] = src_r[i + ((jj < m8) ? jj : (m8-1))];
    uint_t kk8[8], vv8[8];
    #pragma unroll
    for (int jj=0;jj<8;jj++){
      uint_t sr_ = sr8[jj];
      size_t s = (size_t)(sr_ & 0x07FFFFFFu);
      kk8[jj] = *(const uint_t*)(kb + s*DD + (lane<<1));
      vv8[jj] = *(const uint_t*)(vhat + (s*RR + (sr_>>27))*DD + (lane<<1));
    }
    float p8[8];
    #pragma unroll
    for (int jj=0;jj<8;jj++){
      int r = (int)(sr8[jj] >> 27);
      uint_t qw = qn0;
      qw = (r==1) ? qn1 : qw;
      qw = (r==2) ? qn2 : qw;
      qw = (r==3) ? qn3 : qw;
      qw = (r==4) ? qn4 : qw;
      qw = (r==5) ? qn5 : qw;
      uint_t kw = kk8[jj];
      float pp = bf2f((ushort_t)(kw & 0xffffu))*bf2f((ushort_t)(qw & 0xffffu))
               + bf2f((ushort_t)(kw >> 16))   *bf2f((ushort_t)(qw >> 16));
      #pragma unroll
      for (int off=1; off<16; off<<=1) pp += __shfl_xor(pp, off);
      p8[jj] = (jj < m8) ? pp : -1e30f;
    }
    float mb = p8[0];
    #pragma unroll
    for (int jj=1;jj<8;jj++) mb = fmaxf(mb, p8[jj]);
    float mnew = fmaxf(m, mb);
    float corr = __expf(m - mnew);
    den *= corr; ac0 *= corr; ac1 *= corr;
    m = mnew;
    #pragma unroll
    for (int jj=0;jj<8;jj++){
      float ex = __expf(p8[jj] - m);
      den += ex;
      ac0 += ex * bf2f((ushort_t)(vv8[jj] & 0xffffu));
      ac1 += ex * bf2f((ushort_t)(vv8[jj] >> 16));
    }
  }
  float inv = (den > 0.f) ? 1.f/den : 0.f;
  uint_t packed = (uint_t)f2bf(ac0*inv) | ((uint_t)f2bf(ac1*inv) << 16);
  *(uint_t*)(agg16 + (size_t)n*DD + (lane<<1)) = packed;
}

// ---------------- Wa GEMM via MFMA + skip gate + LayerNorm ----------------
__global__ __launch_bounds__(256) void ha_kernel(
    const ushort_t* __restrict__ agg16, const float* __restrict__ x, const int* __restrict__ ntype,
    const float* __restrict__ Wa, const ushort_t* __restrict__ Waf, const float* __restrict__ skipl,
    const float* __restrict__ lng, const float* __restrict__ lnb,
    float* __restrict__ xout)
{
  __shared__ ushort_t as[16][132];
  __shared__ float xs[16][132];
  __shared__ int nts[16];
  int tid = threadIdx.x;
  int n0 = blockIdx.x * 16;
  {
    int row = tid >> 4, col = (tid & 15) * 8;
    uint4 t4 = *(const uint4*)(agg16 + (size_t)(n0+row)*DD + col);
    *(uint2*)&as[row][col]   = make_uint2(t4.x, t4.y);
    *(uint2*)&as[row][col+4] = make_uint2(t4.z, t4.w);
  }
  if (tid < 16) nts[tid] = ntype[n0 + tid];
  __syncthreads();
  int t0 = nts[0];
  bool uni = true;
  #pragma unroll
  for (int j=1;j<16;j++) uni = uni && (nts[j] == t0);

  if (uni){
    int lane = tid & 63, w = tid >> 6;
    int m = lane & 15, kg = lane >> 4;
    float4_t acc0{0.f,0.f,0.f,0.f}, acc1{0.f,0.f,0.f,0.f};
    const ushort_t* waf = Waf + (size_t)t0*16384;
    int tA = 2*w, tB = 2*w+1;
    union U8 { struct { uint2 lo, hi; } u; short8_t s; uint4 q; };
    #pragma unroll
    for (int ks=0; ks<4; ks++){
      U8 a_;
      a_.u.lo = *(const uint2*)&as[m][ks*32 + kg*4];
      a_.u.hi = *(const uint2*)&as[m][ks*32 + kg*4 + 16];
      U8 b0, b1;
      b0.q = *(const uint4*)(waf + ((((tA*4 + ks)*4 + kg) << 7) + (m << 3)));
      b1.q = *(const uint4*)(waf + ((((tB*4 + ks)*4 + kg) << 7) + (m << 3)));
      acc0 = __builtin_amdgcn_mfma_f32_16x16x32_bf16(b0.s, a_.s, acc0, 0,0,0);
      acc1 = __builtin_amdgcn_mfma_f32_16x16x32_bf16(b1.s, a_.s, acc1, 0,0,0);
    }
    float sk = 1.f/(1.f + __expf(-skipl[t0]));
    int cA = tA*16 + (kg<<2), cB = tB*16 + (kg<<2);
    #pragma unroll
    for (int i=0;i<4;i++){
      float xva = x[(size_t)(n0+m)*DD + cA + i];
      float xvb = x[(size_t)(n0+m)*DD + cB + i];
      xs[m][cA+i] = acc0[i]*sk + xva*(2.f - sk);
      xs[m][cB+i] = acc1[i]*sk + xvb*(2.f - sk);
    }
  } else {
    int c = tid & 127, nb = (tid >> 7) * 8;
    float acc[8];
    #pragma unroll
    for (int j=0;j<8;j++) acc[j]=0.f;
    #pragma unroll
    for (int j=0;j<8;j++){
      int t = nts[nb+j];
      const float* wa = Wa + (size_t)t*DD*DD + c;
      float sacc2 = 0.f;
      for (int d=0; d<DD; d++)
        sacc2 += bf2f(as[nb+j][d]) * wa[d*DD];
      acc[j] = sacc2;
    }
    #pragma unroll
    for (int j=0;j<8;j++){
      int n = n0 + nb + j;
      float sk2 = 1.f/(1.f + __expf(-skipl[nts[nb+j]]));
      float xv = x[(size_t)n*DD + c];
      xs[nb+j][c] = acc[j]*sk2 + xv*(2.f - sk2);
    }
  }
  __syncthreads();
  int lane = tid & 63;
  int r0 = tid >> 6;
  #pragma unroll
  for (int rr = r0; rr < 16; rr += 4){
    float t0v = xs[rr][lane], t1v = xs[rr][lane+64];
    float s = t0v + t1v;
    #pragma unroll
    for (int off=32; off>0; off>>=1) s += __shfl_xor(s, off);
    float mu = s * (1.f/DD);
    float d0 = t0v-mu, d1 = t1v-mu;
    float vs = d0*d0 + d1*d1;
    #pragma unroll
    for (int off=32; off>0; off>>=1) vs += __shfl_xor(vs, off);
    float inv = rsqrtf(vs*(1.f/DD) + EPSF);
    size_t base = (size_t)(n0+rr)*DD;
    xout[base+lane]    = d0*inv*lng[lane]    + lnb[lane];
    xout[base+lane+64] = d1*inv*lng[lane+64] + lnb[lane+64];
  }
}

// ---------------- final mix + LayerNorm ----------------
__global__ __launch_bounds__(256) void final_kernel(
    const float* __restrict__ x1, const float* __restrict__ x2,
    const float* __restrict__ aggw, const float* __restrict__ g, const float* __restrict__ b,
    float* __restrict__ out)
{
  int lane = threadIdx.x & 63;
  int n = blockIdx.x*4 + (threadIdx.x >> 6);
  float a0 = aggw[0], a1 = aggw[1];
  float m = fmaxf(a0, a1);
  float e0 = __expf(a0-m), e1 = __expf(a1-m);
  float inv01 = 1.f/(e0+e1);
  float w0 = e0*inv01, w1 = e1*inv01;
  size_t base = (size_t)n*DD;
  float t0 = w0*x1[base+lane]    + w1*x2[base+lane];
  float t1 = w0*x1[base+lane+64] + w1*x2[base+lane+64];
  float s = t0 + t1;
  #pragma unroll
  for (int off=32; off>0; off>>=1) s += __shfl_xor(s, off);
  float mu = s * (1.f/DD);
  float d0 = t0-mu, d1 = t1-mu;
  float vs = d0*d0 + d1*d1;
  #pragma unroll
  for (int off=32; off>0; off>>=1) vs += __shfl_xor(vs, off);
  float invv = rsqrtf(vs*(1.f/DD) + EPSF);
  out[base+lane]    = d0*invv*g[lane]    + b[lane];
  out[base+lane+64] = d1*invv*g[lane+64] + b[lane+64];
}

extern "C" void kernel_launch(void* const* d_in, const int* in_sizes, int n_in,
                              void* d_out, int out_size, void* d_ws, size_t ws_size,
                              hipStream_t stream)
{
  (void)in_sizes; (void)n_in; (void)out_size; (void)ws_size;
  const float* h_in  = (const float*)d_in[0];
  const int*   src   = (const int*)d_in[1];
  const int*   dst   = (const int*)d_in[2];
  const int*   ntype = (const int*)d_in[3];
  const int*   etype = (const int*)d_in[4];
  const float* Wk    = (const float*)d_in[5];
  const float* Wq    = (const float*)d_in[6];
  const float* Wv    = (const float*)d_in[7];
  const float* Wa    = (const float*)d_in[8];
  const float* Watt  = (const float*)d_in[9];
  const float* Wmsg  = (const float*)d_in[10];
  const float* pri   = (const float*)d_in[11];
  const float* skp   = (const float*)d_in[12];
  const float* lng   = (const float*)d_in[13];
  const float* lnb   = (const float*)d_in[14];
  const float* aggw  = (const float*)d_in[15];
  const float* aggg  = (const float*)d_in[16];
  const float* aggb_ = (const float*)d_in[17];

  size_t P = (size_t)NN*DD;
  ushort_t* kb16 = (ushort_t*)d_ws;                 // P bf16
  ushort_t* qh   = kb16 + P;                        // N*R*D bf16
  ushort_t* vhat = qh + (size_t)NN*RR*DD;           // N*R*D bf16
  ushort_t* agg16 = vhat + (size_t)NN*RR*DD;        // P bf16
  float* out0  = (float*)(agg16 + P);               // P f32
  int* rowptr = (int*)(out0 + P);
  int* cnt    = rowptr + NN + 1;
  uint_t* srcr = (uint_t*)(cnt + NN);               // NE packed
  ushort_t* wkF = (ushort_t*)(srcr + NE);           // T*D*D bf16 each (fragment order)
  ushort_t* wqF = wkF + (size_t)TT*DD*DD;
  ushort_t* wvF = wqF + (size_t)TT*DD*DD;
  ushort_t* waF = wvF + (size_t)TT*DD*DD;
  ushort_t* wattF = waF + (size_t)TT*DD*DD;         // H*R*32*32 bf16 (fragment order)
  ushort_t* wmsgF = wattF + (size_t)HH*RR*DHH*DHH;  // H*R*32*32 bf16 (fragment order)
  float* xout = (float*)d_out;

  // CSR by dst
  hipMemsetAsync(cnt, 0, NN*sizeof(int), stream);
  hist_kernel<<<(NE+255)/256, 256, 0, stream>>>(dst, cnt);
  scan_kernel<<<1, 1024, 0, stream>>>(cnt, rowptr);
  hipMemsetAsync(cnt, 0, NN*sizeof(int), stream);
  scatter_kernel<<<(NE+255)/256, 256, 0, stream>>>(dst, src, etype, rowptr, cnt, srcr);

  const float* x = h_in;
  for (int l=0; l<LL; l++){
    const float* Wk_l  = Wk  + (size_t)l*TT*DD*DD;
    const float* Wq_l  = Wq  + (size_t)l*TT*DD*DD;
    const float* Wv_l  = Wv  + (size_t)l*TT*DD*DD;
    const float* Wa_l  = Wa  + (size_t)l*TT*DD*DD;
    const float* Wat_l = Watt + (size_t)l*HH*RR*DHH*DHH;
    const float* Wms_l = Wmsg + (size_t)l*HH*RR*DHH*DHH;
    const float* pri_l = pri + (size_t)l*HH*RR;
    const float* skp_l = skp + (size_t)l*TT;

    wprep_kernel<<<(TT*DD*DD+255)/256, 256, 0, stream>>>(Wk_l, Wq_l, Wv_l, Wa_l,
                                                         wkF, wqF, wvF, waF);
    wprep2_kernel<<<(HH*RR*DHH*DHH+255)/256, 256, 0, stream>>>(Wat_l, Wms_l, wattF, wmsgF);
    kqv_kernel<<<NN/16, 256, 0, stream>>>(x, ntype, Wk_l, Wq_l, Wv_l, wkF, wqF, wvF,
                                          wattF, wmsgF, pri_l, kb16, qh, vhat);
    reduce_kernel<<<(NN+3)/4, 256, 0, stream>>>(kb16, qh, vhat, rowptr, srcr, agg16);
    float* xo = (l == 0) ? out0 : xout;
    ha_kernel<<<NN/16, 256, 0, stream>>>(agg16, x, ntype, Wa_l, waF, skp_l,
                                         lng + (size_t)l*DD, lnb + (size_t)l*DD, xo);
    x = xo;
  }
  final_kernel<<<NN/4, 256, 0, stream>>>(out0, xout, aggw, aggg, aggb_, xout);
}

// Round 28
// 381.064 us; speedup vs baseline: 1.2518x; 1.2496x over previous
//
#include <hip/hip_runtime.h>

#define NN 50000
#define NE 400000
#define DD 128
#define HH 4
#define DHH 32
#define TT 3
#define RR 6
#define LL 2
#define EPSF 1e-5f
#define NSB 196   // scan blocks = ceil(NN/256)

typedef unsigned short ushort_t;
typedef unsigned int uint_t;
typedef __attribute__((ext_vector_type(8))) short short8_t;
typedef __attribute__((ext_vector_type(4))) float float4_t;

__device__ inline ushort_t f2bf(float f){
  union { float f; uint_t u; } x; x.f = f;
  uint_t r = x.u + 0x7fffu + ((x.u >> 16) & 1u);
  return (ushort_t)(r >> 16);
}
__device__ inline float bf2f(ushort_t u){
  union { uint_t u; float f; } x; x.u = ((uint_t)u) << 16;
  return x.f;
}
__device__ inline uint_t pack2(float a, float b){
  return (uint_t)f2bf(a) | ((uint_t)f2bf(b) << 16);
}

// ---------------- CSR build ----------------
__global__ void hist_kernel(const int* __restrict__ dst, int* __restrict__ cnt){
  int e = blockIdx.x*256 + threadIdx.x;
  if (e < NE) atomicAdd(&cnt[dst[e]], 1);
}

// parallel scan, pass A: block-local inclusive scan (coalesced), block totals
__global__ __launch_bounds__(256) void scanA_kernel(const int* __restrict__ deg,
                                                    int* __restrict__ rowptr,
                                                    int* __restrict__ bsum){
  __shared__ int wsum[4];
  int tid = threadIdx.x, lane = tid & 63, w = tid >> 6;
  int i = blockIdx.x*256 + tid;
  int v = (i < NN) ? deg[i] : 0;
  int s = v;
  #pragma unroll
  for (int off=1; off<64; off<<=1){ int t = __shfl_up(s, off); if (lane >= off) s += t; }
  if (lane == 63) wsum[w] = s;
  __syncthreads();
  if (w == 0 && lane < 4){
    int t = wsum[lane];
    #pragma unroll
    for (int off=1; off<4; off<<=1){ int u = __shfl_up(t, off); if (lane >= off) t += u; }
    wsum[lane] = t;
  }
  __syncthreads();
  int waveOff = (w == 0) ? 0 : wsum[w-1];
  int incl = s + waveOff;
  if (i < NN) rowptr[i+1] = incl;
  if (tid == 255) bsum[blockIdx.x] = incl;
}

// pass B: exclusive scan of the 196 block sums
__global__ __launch_bounds__(256) void scanB_kernel(const int* __restrict__ bsum,
                                                    int* __restrict__ boff){
  __shared__ int wsum[4];
  int tid = threadIdx.x, lane = tid & 63, w = tid >> 6;
  int v = (tid < NSB) ? bsum[tid] : 0;
  int s = v;
  #pragma unroll
  for (int off=1; off<64; off<<=1){ int t = __shfl_up(s, off); if (lane >= off) s += t; }
  if (lane == 63) wsum[w] = s;
  __syncthreads();
  if (w == 0 && lane < 4){
    int t = wsum[lane];
    #pragma unroll
    for (int off=1; off<4; off<<=1){ int u = __shfl_up(t, off); if (lane >= off) t += u; }
    wsum[lane] = t;
  }
  __syncthreads();
  int waveOff = (w == 0) ? 0 : wsum[w-1];
  if (tid < NSB) boff[tid] = (s + waveOff) - v;   // exclusive prefix
}

// pass C: add block offsets
__global__ __launch_bounds__(256) void scanC_kernel(int* __restrict__ rowptr,
                                                    const int* __restrict__ boff){
  int i = blockIdx.x*256 + threadIdx.x;
  if (i < NN) rowptr[i+1] += boff[blockIdx.x];
  if (i == 0) rowptr[0] = 0;
}

// scatter: packed (src | etype<<27) in CSR order
__global__ void scatter_kernel(const int* __restrict__ dst, const int* __restrict__ src,
                               const int* __restrict__ etype, const int* __restrict__ rowptr,
                               int* __restrict__ cnt, uint_t* __restrict__ sr){
  int e = blockIdx.x*256 + threadIdx.x;
  if (e < NE){
    int d = dst[e];
    int pos = rowptr[d] + atomicAdd(&cnt[d], 1);
    sr[pos] = (uint_t)src[e] | ((uint_t)etype[e] << 27);
  }
}

// ---------------- W prep: FRAGMENT-ORDER bf16 layouts (Wk,Wq,Wv,Wa) ----------------
__global__ void wprep_kernel(const float* __restrict__ Wk, const float* __restrict__ Wq,
                             const float* __restrict__ Wv, const float* __restrict__ Wa,
                             ushort_t* __restrict__ Wkf, ushort_t* __restrict__ Wqf,
                             ushort_t* __restrict__ Wvf, ushort_t* __restrict__ Waf){
  int i = blockIdx.x*256 + threadIdx.x;
  if (i < TT*DD*DD){
    int j = i & 7, m = (i>>3)&15, kg = (i>>7)&3, ks = (i>>9)&3, tile = (i>>11)&7, t = i>>14;
    int d = ks*32 + kg*4 + (j&3) + ((j>>2)<<4);
    int o = tile*16 + m;
    size_t srcI = (size_t)t*16384 + (size_t)d*DD + o;
    Wkf[i] = f2bf(Wk[srcI]);
    Wqf[i] = f2bf(Wq[srcI]);
    Wvf[i] = f2bf(Wv[srcI]);
    Waf[i] = f2bf(Wa[srcI]);
  }
}

__global__ void wprep2_kernel(const float* __restrict__ Watt, const float* __restrict__ Wmsg,
                              ushort_t* __restrict__ Wattf, ushort_t* __restrict__ Wmsgf){
  int i = blockIdx.x*256 + threadIdx.x;
  if (i < HH*RR*DHH*DHH){
    int j = i & 7, m = (i>>3)&15, kg = (i>>7)&3;
    int tile = (i>>9) % 12, h = i / 6144;
    int nout = tile*16 + m;
    int r = nout >> 5, dd = nout & 31;
    int k = kg*4 + (j&3) + ((j>>2)<<4);
    Wattf[i] = f2bf(Watt[(((h*RR + r)*DHH + dd)<<5) + k]);
    Wmsgf[i] = f2bf(Wmsg[(((h*RR + r)*DHH + k)<<5) + dd]);
  }
}

// ---------------- fused K/Q/V + qhat + vhat; ping-pong staging, L2-resident stores ----------------
__global__ __launch_bounds__(256) void kqv_kernel(
    const float* __restrict__ x, const int* __restrict__ ntype,
    const float* __restrict__ Wk, const float* __restrict__ Wq, const float* __restrict__ Wv,
    const ushort_t* __restrict__ Wkf, const ushort_t* __restrict__ Wqf, const ushort_t* __restrict__ Wvf,
    const ushort_t* __restrict__ Wattf, const ushort_t* __restrict__ Wmsgf,
    const float* __restrict__ pri,
    ushort_t* __restrict__ kout, ushort_t* __restrict__ qh, ushort_t* __restrict__ vhat)
{
  __shared__ int nts[16];
  __shared__ ushort_t smem[24704];      // 49.4 KB
  ushort_t* xs_ = smem;                 // [16][132] phase B (aliased by stg1)
  ushort_t* qs_ = smem + 2112;
  ushort_t* vs_ = smem + 4224;
  ushort_t* ks_ = smem + 6336;          // ends 8448
  ushort_t* stg1 = smem;                // [16][772] staging for qh
  ushort_t* stg2 = smem + 12352;        // [16][772] staging for vhat
  int tid = threadIdx.x;
  int n0 = blockIdx.x * 16;
  if (tid < 16) nts[tid] = ntype[n0 + tid];
  #pragma unroll
  for (int it=0; it<8; it++){
    int i = tid + it*256;
    xs_[(i>>7)*132 + (i&127)] = f2bf(x[(size_t)n0*DD + i]);
  }
  __syncthreads();
  int t0 = nts[0];
  bool uni = true;
  #pragma unroll
  for (int j=1;j<16;j++) uni = uni && (nts[j] == t0);

  int lane = tid & 63;
  union U8 { struct { uint2 lo, hi; } u; short8_t s; uint4 q; };

  if (uni){
    int w = tid >> 6;
    int m = lane & 15, kg = lane >> 4;
    float4_t acck0{0.f,0.f,0.f,0.f}, acck1{0.f,0.f,0.f,0.f};
    float4_t accq0{0.f,0.f,0.f,0.f}, accq1{0.f,0.f,0.f,0.f};
    float4_t accv0{0.f,0.f,0.f,0.f}, accv1{0.f,0.f,0.f,0.f};
    const ushort_t* wkf = Wkf + (size_t)t0*16384;
    const ushort_t* wqf = Wqf + (size_t)t0*16384;
    const ushort_t* wvf = Wvf + (size_t)t0*16384;
    int tA = 2*w, tB = 2*w+1;
    #pragma unroll
    for (int ks=0; ks<4; ks++){
      U8 a_;
      a_.u.lo = *(const uint2*)&xs_[m*132 + ks*32 + kg*4];
      a_.u.hi = *(const uint2*)&xs_[m*132 + ks*32 + kg*4 + 16];
      int offA = (((tA*4 + ks)*4 + kg) << 7) + (m << 3);
      int offB = (((tB*4 + ks)*4 + kg) << 7) + (m << 3);
      U8 bk0, bk1, bq0, bq1, bv0, bv1;
      bk0.q = *(const uint4*)(wkf + offA);
      bk1.q = *(const uint4*)(wkf + offB);
      bq0.q = *(const uint4*)(wqf + offA);
      bq1.q = *(const uint4*)(wqf + offB);
      bv0.q = *(const uint4*)(wvf + offA);
      bv1.q = *(const uint4*)(wvf + offB);
      acck0 = __builtin_amdgcn_mfma_f32_16x16x32_bf16(bk0.s, a_.s, acck0, 0,0,0);
      acck1 = __builtin_amdgcn_mfma_f32_16x16x32_bf16(bk1.s, a_.s, acck1, 0,0,0);
      accq0 = __builtin_amdgcn_mfma_f32_16x16x32_bf16(bq0.s, a_.s, accq0, 0,0,0);
      accq1 = __builtin_amdgcn_mfma_f32_16x16x32_bf16(bq1.s, a_.s, accq1, 0,0,0);
      accv0 = __builtin_amdgcn_mfma_f32_16x16x32_bf16(bv0.s, a_.s, accv0, 0,0,0);
      accv1 = __builtin_amdgcn_mfma_f32_16x16x32_bf16(bv1.s, a_.s, accv1, 0,0,0);
    }
    int cA = tA*16 + (kg<<2), cB = tB*16 + (kg<<2);
    *(uint2*)(&ks_[m*132 + cA]) = make_uint2(pack2(acck0[0],acck0[1]), pack2(acck0[2],acck0[3]));
    *(uint2*)(&ks_[m*132 + cB]) = make_uint2(pack2(acck1[0],acck1[1]), pack2(acck1[2],acck1[3]));
    *(uint2*)(&qs_[m*132 + cA]) = make_uint2(pack2(accq0[0],accq0[1]), pack2(accq0[2],accq0[3]));
    *(uint2*)(&qs_[m*132 + cB]) = make_uint2(pack2(accq1[0],accq1[1]), pack2(accq1[2],accq1[3]));
    *(uint2*)(&vs_[m*132 + cA]) = make_uint2(pack2(accv0[0],accv0[1]), pack2(accv0[2],accv0[3]));
    *(uint2*)(&vs_[m*132 + cB]) = make_uint2(pack2(accv1[0],accv1[1]), pack2(accv1[2],accv1[3]));
  } else {
    int c = tid & 127, nb = (tid >> 7) * 8;
    float ak[8], aq[8], av[8];
    #pragma unroll
    for (int j=0;j<8;j++){ ak[j]=0.f; aq[j]=0.f; av[j]=0.f; }
    #pragma unroll
    for (int j=0;j<8;j++){
      int t = nts[nb+j];
      const float* wk = Wk + (size_t)t*DD*DD + c;
      const float* wq = Wq + (size_t)t*DD*DD + c;
      const float* wv = Wv + (size_t)t*DD*DD + c;
      float sk=0.f, sq=0.f, sv=0.f;
      for (int d=0; d<DD; d++){
        float xv = bf2f(xs_[(nb+j)*132 + d]);
        sk += xv*wk[d*DD];
        sq += xv*wq[d*DD];
        sv += xv*wv[d*DD];
      }
      ak[j]=sk; aq[j]=sq; av[j]=sv;
    }
    #pragma unroll
    for (int j=0;j<8;j++){
      ks_[(nb+j)*132 + c]=f2bf(ak[j]);
      qs_[(nb+j)*132 + c]=f2bf(aq[j]);
      vs_[(nb+j)*132 + c]=f2bf(av[j]);
    }
  }
  __syncthreads();

  // ---- load phase-C A-frags to regs; copy k tile out (coalesced) ----
  int h = tid >> 6;
  int m = lane & 15, kg = lane >> 4;
  U8 aq_, av_;
  aq_.u.lo = *(const uint2*)&qs_[m*132 + (h<<5) + (kg<<2)];
  aq_.u.hi = *(const uint2*)&qs_[m*132 + (h<<5) + (kg<<2) + 16];
  av_.u.lo = *(const uint2*)&vs_[m*132 + (h<<5) + (kg<<2)];
  av_.u.hi = *(const uint2*)&vs_[m*132 + (h<<5) + (kg<<2) + 16];
  {
    int row = tid >> 4, coff = (tid & 15) * 8;
    uint4 kv4;
    kv4.x = *(const uint_t*)&ks_[row*132 + coff];
    kv4.y = *(const uint_t*)&ks_[row*132 + coff + 2];
    kv4.z = *(const uint_t*)&ks_[row*132 + coff + 4];
    kv4.w = *(const uint_t*)&ks_[row*132 + coff + 6];
    *(uint4*)(kout + (size_t)(n0+row)*DD + coff) = kv4;
  }
  __syncthreads();   // phase-B tiles dead; stg1 may overwrite

  const ushort_t* wqb = Wattf + h*(RR*DHH*DHH);
  const ushort_t* wvb = Wmsgf + h*(RR*DHH*DHH);

  // ---- Phase C-q: qhat MFMAs -> stg1 ----
  #pragma unroll
  for (int nt=0; nt<12; nt++){
    int frag = ((nt*4 + kg)<<7) + (m<<3);
    U8 bq_;
    bq_.q = *(const uint4*)(wqb + frag);
    float4_t accq{0.f,0.f,0.f,0.f};
    accq = __builtin_amdgcn_mfma_f32_16x16x32_bf16(bq_.s, aq_.s, accq, 0,0,0);
    int nout0 = nt*16 + (kg<<2);
    int r = nout0 >> 5, dd0 = nout0 & 31;
    float scale = pri[h*RR + r] * 0.17677669529663687f;
    *(uint2*)(&stg1[m*772 + r*DD + (h<<5) + dd0]) =
        make_uint2(pack2(accq[0]*scale, accq[1]*scale), pack2(accq[2]*scale, accq[3]*scale));
  }
  __syncthreads();

  // ---- overlapped: qh copy-out (stg1) + vhat MFMAs (-> stg2) ----
  #pragma unroll
  for (int it=0; it<6; it++){
    int idx = tid + it*256;
    int row = idx / 96;
    int off = (idx - row*96) * 8;
    uint4 q4;
    q4.x = *(const uint_t*)&stg1[row*772 + off];
    q4.y = *(const uint_t*)&stg1[row*772 + off + 2];
    q4.z = *(const uint_t*)&stg1[row*772 + off + 4];
    q4.w = *(const uint_t*)&stg1[row*772 + off + 6];
    *(uint4*)(qh + (size_t)(n0+row)*768 + off) = q4;
  }
  #pragma unroll
  for (int nt=0; nt<12; nt++){
    int frag = ((nt*4 + kg)<<7) + (m<<3);
    U8 bv_;
    bv_.q = *(const uint4*)(wvb + frag);
    float4_t accv{0.f,0.f,0.f,0.f};
    accv = __builtin_amdgcn_mfma_f32_16x16x32_bf16(bv_.s, av_.s, accv, 0,0,0);
    int nout0 = nt*16 + (kg<<2);
    int r = nout0 >> 5, dd0 = nout0 & 31;
    *(uint2*)(&stg2[m*772 + r*DD + (h<<5) + dd0]) =
        make_uint2(pack2(accv[0],accv[1]), pack2(accv[2],accv[3]));
  }
  __syncthreads();

  // ---- vhat copy-out (stg2) ----
  #pragma unroll
  for (int it=0; it<6; it++){
    int idx = tid + it*256;
    int row = idx / 96;
    int off = (idx - row*96) * 8;
    uint4 v4;
    v4.x = *(const uint_t*)&stg2[row*772 + off];
    v4.y = *(const uint_t*)&stg2[row*772 + off + 2];
    v4.z = *(const uint_t*)&stg2[row*772 + off + 4];
    v4.w = *(const uint_t*)&stg2[row*772 + off + 6];
    *(uint4*)(vhat + (size_t)(n0+row)*768 + off) = v4;
  }
}

// ---------------- fused logits + online-softmax + vhat-reduce (wave/node, 8-wide) ----------------
__global__ __launch_bounds__(256) void reduce_kernel(
    const ushort_t* __restrict__ kb, const ushort_t* __restrict__ qh,
    const ushort_t* __restrict__ vhat,
    const int* __restrict__ rowptr, const uint_t* __restrict__ src_r,
    ushort_t* __restrict__ agg16)
{
  int n = blockIdx.x*4 + (threadIdx.x >> 6);
  if (n >= NN) return;
  int lane = threadIdx.x & 63;
  int b = rowptr[n], e1 = rowptr[n+1];
  const uint_t* qbase = (const uint_t*)(qh + (size_t)n*RR*DD) + lane;
  uint_t qn0 = qbase[0*64], qn1 = qbase[1*64], qn2 = qbase[2*64];
  uint_t qn3 = qbase[3*64], qn4 = qbase[4*64], qn5 = qbase[5*64];
  float m = -1e30f, den = 0.f, ac0 = 0.f, ac1 = 0.f;
  for (int i=b; i<e1; i+=8){
    int m8 = e1 - i; if (m8 > 8) m8 = 8;
    uint_t sr8[8];
    #pragma unroll
    for (int jj=0;jj<8;jj++) sr8[jj] = src_r[i + ((jj < m8) ? jj : (m8-1))];
    uint_t kk8[8], vv8[8];
    #pragma unroll
    for (int jj=0;jj<8;jj++){
      uint_t sr_ = sr8[jj];
      size_t s = (size_t)(sr_ & 0x07FFFFFFu);
      kk8[jj] = *(const uint_t*)(kb + s*DD + (lane<<1));
      vv8[jj] = *(const uint_t*)(vhat + (s*RR + (sr_>>27))*DD + (lane<<1));
    }
    float p8[8];
    #pragma unroll
    for (int jj=0;jj<8;jj++){
      int r = (int)(sr8[jj] >> 27);
      uint_t qw = qn0;
      qw = (r==1) ? qn1 : qw;
      qw = (r==2) ? qn2 : qw;
      qw = (r==3) ? qn3 : qw;
      qw = (r==4) ? qn4 : qw;
      qw = (r==5) ? qn5 : qw;
      uint_t kw = kk8[jj];
      float pp = bf2f((ushort_t)(kw & 0xffffu))*bf2f((ushort_t)(qw & 0xffffu))
               + bf2f((ushort_t)(kw >> 16))   *bf2f((ushort_t)(qw >> 16));
      #pragma unroll
      for (int off=1; off<16; off<<=1) pp += __shfl_xor(pp, off);
      p8[jj] = (jj < m8) ? pp : -1e30f;
    }
    float mb = p8[0];
    #pragma unroll
    for (int jj=1;jj<8;jj++) mb = fmaxf(mb, p8[jj]);
    float mnew = fmaxf(m, mb);
    float corr = __expf(m - mnew);
    den *= corr; ac0 *= corr; ac1 *= corr;
    m = mnew;
    #pragma unroll
    for (int jj=0;jj<8;jj++){
      float ex = __expf(p8[jj] - m);
      den += ex;
      ac0 += ex * bf2f((ushort_t)(vv8[jj] & 0xffffu));
      ac1 += ex * bf2f((ushort_t)(vv8[jj] >> 16));
    }
  }
  float inv = (den > 0.f) ? 1.f/den : 0.f;
  uint_t packed = (uint_t)f2bf(ac0*inv) | ((uint_t)f2bf(ac1*inv) << 16);
  *(uint_t*)(agg16 + (size_t)n*DD + (lane<<1)) = packed;
}

// ---------------- Wa GEMM via MFMA + skip gate + LayerNorm ----------------
__global__ __launch_bounds__(256) void ha_kernel(
    const ushort_t* __restrict__ agg16, const float* __restrict__ x, const int* __restrict__ ntype,
    const float* __restrict__ Wa, const ushort_t* __restrict__ Waf, const float* __restrict__ skipl,
    const float* __restrict__ lng, const float* __restrict__ lnb,
    float* __restrict__ xout)
{
  __shared__ ushort_t as[16][132];
  __shared__ float xs[16][132];
  __shared__ int nts[16];
  int tid = threadIdx.x;
  int n0 = blockIdx.x * 16;
  {
    int row = tid >> 4, col = (tid & 15) * 8;
    uint4 t4 = *(const uint4*)(agg16 + (size_t)(n0+row)*DD + col);
    *(uint2*)&as[row][col]   = make_uint2(t4.x, t4.y);
    *(uint2*)&as[row][col+4] = make_uint2(t4.z, t4.w);
  }
  if (tid < 16) nts[tid] = ntype[n0 + tid];
  __syncthreads();
  int t0 = nts[0];
  bool uni = true;
  #pragma unroll
  for (int j=1;j<16;j++) uni = uni && (nts[j] == t0);

  if (uni){
    int lane = tid & 63, w = tid >> 6;
    int m = lane & 15, kg = lane >> 4;
    float4_t acc0{0.f,0.f,0.f,0.f}, acc1{0.f,0.f,0.f,0.f};
    const ushort_t* waf = Waf + (size_t)t0*16384;
    int tA = 2*w, tB = 2*w+1;
    union U8 { struct { uint2 lo, hi; } u; short8_t s; uint4 q; };
    #pragma unroll
    for (int ks=0; ks<4; ks++){
      U8 a_;
      a_.u.lo = *(const uint2*)&as[m][ks*32 + kg*4];
      a_.u.hi = *(const uint2*)&as[m][ks*32 + kg*4 + 16];
      U8 b0, b1;
      b0.q = *(const uint4*)(waf + ((((tA*4 + ks)*4 + kg) << 7) + (m << 3)));
      b1.q = *(const uint4*)(waf + ((((tB*4 + ks)*4 + kg) << 7) + (m << 3)));
      acc0 = __builtin_amdgcn_mfma_f32_16x16x32_bf16(b0.s, a_.s, acc0, 0,0,0);
      acc1 = __builtin_amdgcn_mfma_f32_16x16x32_bf16(b1.s, a_.s, acc1, 0,0,0);
    }
    float sk = 1.f/(1.f + __expf(-skipl[t0]));
    int cA = tA*16 + (kg<<2), cB = tB*16 + (kg<<2);
    #pragma unroll
    for (int i=0;i<4;i++){
      float xva = x[(size_t)(n0+m)*DD + cA + i];
      float xvb = x[(size_t)(n0+m)*DD + cB + i];
      xs[m][cA+i] = acc0[i]*sk + xva*(2.f - sk);
      xs[m][cB+i] = acc1[i]*sk + xvb*(2.f - sk);
    }
  } else {
    int c = tid & 127, nb = (tid >> 7) * 8;
    float acc[8];
    #pragma unroll
    for (int j=0;j<8;j++) acc[j]=0.f;
    #pragma unroll
    for (int j=0;j<8;j++){
      int t = nts[nb+j];
      const float* wa = Wa + (size_t)t*DD*DD + c;
      float sacc2 = 0.f;
      for (int d=0; d<DD; d++)
        sacc2 += bf2f(as[nb+j][d]) * wa[d*DD];
      acc[j] = sacc2;
    }
    #pragma unroll
    for (int j=0;j<8;j++){
      int n = n0 + nb + j;
      float sk2 = 1.f/(1.f + __expf(-skipl[nts[nb+j]]));
      float xv = x[(size_t)n*DD + c];
      xs[nb+j][c] = acc[j]*sk2 + xv*(2.f - sk2);
    }
  }
  __syncthreads();
  int lane = tid & 63;
  int r0 = tid >> 6;
  #pragma unroll
  for (int rr = r0; rr < 16; rr += 4){
    float t0v = xs[rr][lane], t1v = xs[rr][lane+64];
    float s = t0v + t1v;
    #pragma unroll
    for (int off=32; off>0; off>>=1) s += __shfl_xor(s, off);
    float mu = s * (1.f/DD);
    float d0 = t0v-mu, d1 = t1v-mu;
    float vs = d0*d0 + d1*d1;
    #pragma unroll
    for (int off=32; off>0; off>>=1) vs += __shfl_xor(vs, off);
    float inv = rsqrtf(vs*(1.f/DD) + EPSF);
    size_t base = (size_t)(n0+rr)*DD;
    xout[base+lane]    = d0*inv*lng[lane]    + lnb[lane];
    xout[base+lane+64] = d1*inv*lng[lane+64] + lnb[lane+64];
  }
}

// ---------------- final mix + LayerNorm ----------------
__global__ __launch_bounds__(256) void final_kernel(
    const float* __restrict__ x1, const float* __restrict__ x2,
    const float* __restrict__ aggw, const float* __restrict__ g, const float* __restrict__ b,
    float* __restrict__ out)
{
  int lane = threadIdx.x & 63;
  int n = blockIdx.x*4 + (threadIdx.x >> 6);
  float a0 = aggw[0], a1 = aggw[1];
  float m = fmaxf(a0, a1);
  float e0 = __expf(a0-m), e1 = __expf(a1-m);
  float inv01 = 1.f/(e0+e1);
  float w0 = e0*inv01, w1 = e1*inv01;
  size_t base = (size_t)n*DD;
  float t0 = w0*x1[base+lane]    + w1*x2[base+lane];
  float t1 = w0*x1[base+lane+64] + w1*x2[base+lane+64];
  float s = t0 + t1;
  #pragma unroll
  for (int off=32; off>0; off>>=1) s += __shfl_xor(s, off);
  float mu = s * (1.f/DD);
  float d0 = t0-mu, d1 = t1-mu;
  float vs = d0*d0 + d1*d1;
  #pragma unroll
  for (int off=32; off>0; off>>=1) vs += __shfl_xor(vs, off);
  float invv = rsqrtf(vs*(1.f/DD) + EPSF);
  out[base+lane]    = d0*invv*g[lane]    + b[lane];
  out[base+lane+64] = d1*invv*g[lane+64] + b[lane+64];
}

extern "C" void kernel_launch(void* const* d_in, const int* in_sizes, int n_in,
                              void* d_out, int out_size, void* d_ws, size_t ws_size,
                              hipStream_t stream)
{
  (void)in_sizes; (void)n_in; (void)out_size; (void)ws_size;
  const float* h_in  = (const float*)d_in[0];
  const int*   src   = (const int*)d_in[1];
  const int*   dst   = (const int*)d_in[2];
  const int*   ntype = (const int*)d_in[3];
  const int*   etype = (const int*)d_in[4];
  const float* Wk    = (const float*)d_in[5];
  const float* Wq    = (const float*)d_in[6];
  const float* Wv    = (const float*)d_in[7];
  const float* Wa    = (const float*)d_in[8];
  const float* Watt  = (const float*)d_in[9];
  const float* Wmsg  = (const float*)d_in[10];
  const float* pri   = (const float*)d_in[11];
  const float* skp   = (const float*)d_in[12];
  const float* lng   = (const float*)d_in[13];
  const float* lnb   = (const float*)d_in[14];
  const float* aggw  = (const float*)d_in[15];
  const float* aggg  = (const float*)d_in[16];
  const float* aggb_ = (const float*)d_in[17];

  size_t P = (size_t)NN*DD;
  ushort_t* kb16 = (ushort_t*)d_ws;                 // P bf16
  ushort_t* qh   = kb16 + P;                        // N*R*D bf16
  ushort_t* vhat = qh + (size_t)NN*RR*DD;           // N*R*D bf16
  ushort_t* agg16 = vhat + (size_t)NN*RR*DD;        // P bf16
  float* out0  = (float*)(agg16 + P);               // P f32
  int* rowptr = (int*)(out0 + P);
  int* cnt    = rowptr + NN + 1;
  uint_t* srcr = (uint_t*)(cnt + NN);               // NE packed
  ushort_t* wkF = (ushort_t*)(srcr + NE);           // T*D*D bf16 each (fragment order)
  ushort_t* wqF = wkF + (size_t)TT*DD*DD;
  ushort_t* wvF = wqF + (size_t)TT*DD*DD;
  ushort_t* waF = wvF + (size_t)TT*DD*DD;
  ushort_t* wattF = waF + (size_t)TT*DD*DD;         // H*R*32*32 bf16 (fragment order)
  ushort_t* wmsgF = wattF + (size_t)HH*RR*DHH*DHH;  // H*R*32*32 bf16 (fragment order)
  int* bsum = (int*)(wmsgF + (size_t)HH*RR*DHH*DHH);// NSB ints
  int* boff = bsum + NSB;                           // NSB ints
  float* xout = (float*)d_out;

  // CSR by dst (parallel 3-pass scan)
  hipMemsetAsync(cnt, 0, NN*sizeof(int), stream);
  hist_kernel<<<(NE+255)/256, 256, 0, stream>>>(dst, cnt);
  scanA_kernel<<<NSB, 256, 0, stream>>>(cnt, rowptr, bsum);
  scanB_kernel<<<1, 256, 0, stream>>>(bsum, boff);
  scanC_kernel<<<NSB, 256, 0, stream>>>(rowptr, boff);
  hipMemsetAsync(cnt, 0, NN*sizeof(int), stream);
  scatter_kernel<<<(NE+255)/256, 256, 0, stream>>>(dst, src, etype, rowptr, cnt, srcr);

  const float* x = h_in;
  for (int l=0; l<LL; l++){
    const float* Wk_l  = Wk  + (size_t)l*TT*DD*DD;
    const float* Wq_l  = Wq  + (size_t)l*TT*DD*DD;
    const float* Wv_l  = Wv  + (size_t)l*TT*DD*DD;
    const float* Wa_l  = Wa  + (size_t)l*TT*DD*DD;
    const float* Wat_l = Watt + (size_t)l*HH*RR*DHH*DHH;
    const float* Wms_l = Wmsg + (size_t)l*HH*RR*DHH*DHH;
    const float* pri_l = pri + (size_t)l*HH*RR;
    const float* skp_l = skp + (size_t)l*TT;

    wprep_kernel<<<(TT*DD*DD+255)/256, 256, 0, stream>>>(Wk_l, Wq_l, Wv_l, Wa_l,
                                                         wkF, wqF, wvF, waF);
    wprep2_kernel<<<(HH*RR*DHH*DHH+255)/256, 256, 0, stream>>>(Wat_l, Wms_l, wattF, wmsgF);
    kqv_kernel<<<NN/16, 256, 0, stream>>>(x, ntype, Wk_l, Wq_l, Wv_l, wkF, wqF, wvF,
                                          wattF, wmsgF, pri_l, kb16, qh, vhat);
    reduce_kernel<<<(NN+3)/4, 256, 0, stream>>>(kb16, qh, vhat, rowptr, srcr, agg16);
    float* xo = (l == 0) ? out0 : xout;
    ha_kernel<<<NN/16, 256, 0, stream>>>(agg16, x, ntype, Wa_l, waF, skp_l,
                                         lng + (size_t)l*DD, lnb + (size_t)l*DD, xo);
    x = xo;
  }
  final_kernel<<<NN/4, 256, 0, stream>>>(out0, xout, aggw, aggg, aggb_, xout);
}